// Round 9
// baseline (224.560 us; speedup 1.0000x reference)
//
#include <hip/hip_runtime.h>
#include <math.h>

#define NB 8192      // batch rows
#define NC 1000      // classes
#define NF4 250      // NC / 4 float4s per row

// ws layout (floats, stride NB):
//  [0..4]   margin per branch
//  [5..9]   gathered (raw) per branch
//  [10..14] KD per branch
//  [15]     CE
//  [16]     row min of gathered over 4 real teachers
//  [17]     row max of row-maxes over 4 real teachers
//  [18*NB + 0] shift  (written by k_minmax)
//  [18*NB + 1] maxp   (written by k_minmax)
//  [20*NB ...] probe sink (never read back)

#define LOG2E 1.4426950408889634f
#define LN2   0.6931471805599453f

__device__ __forceinline__ float fexp2(float x) { return __builtin_amdgcn_exp2f(x); }
__device__ __forceinline__ float flog2(float x) { return __builtin_amdgcn_logf(x); }

// ---------------- DPP wave reductions (VALU pipe, not DS) ----------------
template <int CTRL>
__device__ __forceinline__ float dpp_mov(float v, float ident) {
  return __uint_as_float((unsigned)__builtin_amdgcn_update_dpp(
      (int)__float_as_uint(ident), (int)__float_as_uint(v), CTRL, 0xF, 0xF,
      false));
}

__device__ __forceinline__ float dppredsum(float v) {
  v += dpp_mov<0x111>(v, 0.f);
  v += dpp_mov<0x112>(v, 0.f);
  v += dpp_mov<0x114>(v, 0.f);
  v += dpp_mov<0x118>(v, 0.f);
  v += dpp_mov<0x142>(v, 0.f);
  v += dpp_mov<0x143>(v, 0.f);
  return v;  // lane 63 = full sum
}

__device__ __forceinline__ void dppredtop2(float& t1, float& t2) {
  const float NI = -INFINITY;
#define T2STEP(C)                                   \
  {                                                 \
    float i1 = dpp_mov<C>(t1, NI);                  \
    float i2 = dpp_mov<C>(t2, NI);                  \
    t2 = fmaxf(fmaxf(t2, i2), fminf(t1, i1));       \
    t1 = fmaxf(t1, i1);                             \
  }
  T2STEP(0x111) T2STEP(0x112) T2STEP(0x114) T2STEP(0x118)
  T2STEP(0x142) T2STEP(0x143)
#undef T2STEP
}

// shfl-based helpers (only used in the tiny finalize kernels)
__device__ __forceinline__ float wredsum(float v) {
#pragma unroll
  for (int m = 32; m >= 1; m >>= 1) v += __shfl_xor(v, m, 64);
  return v;
}
__device__ __forceinline__ float wredmax(float v) {
#pragma unroll
  for (int m = 32; m >= 1; m >>= 1) v = fmaxf(v, __shfl_xor(v, m, 64));
  return v;
}
__device__ __forceinline__ float wredmin(float v) {
#pragma unroll
  for (int m = 32; m >= 1; m >>= 1) v = fminf(v, __shfl_xor(v, m, 64));
  return v;
}
__device__ __forceinline__ float f4get(const float4& v, int e) {
  return e == 0 ? v.x : e == 1 ? v.y : e == 2 ? v.z : v.w;
}

// ---------------- BW PROBE ----------------
// Copy-style pure streaming read of all 5 tensors: grid-stride, ~8
// independent iterations per thread, 5 loads in flight per iteration.
// Measures the access pattern's achievable BW, decoupled from the real
// kernel's compute structure. Checksum (DPP-reduced, lane63) written to an
// unused ws region so the loads can't be DCE'd.
__global__ __launch_bounds__(256) void k_probe(
    const float4* __restrict__ a, const float4* __restrict__ b,
    const float4* __restrict__ c, const float4* __restrict__ d,
    const float4* __restrict__ e, float* __restrict__ sink) {
  const int n = NB * NC / 4;  // 2,048,000 float4 per tensor
  const int stride = gridDim.x * 256;
  float ax = 0.f;
#pragma unroll 2
  for (int i = blockIdx.x * 256 + threadIdx.x; i < n; i += stride) {
    float4 va = a[i], vb = b[i], vc = c[i], vd = d[i], ve = e[i];
    ax += (va.x + va.y + va.z + va.w) + (vb.x + vb.y + vb.z + vb.w) +
          (vc.x + vc.y + vc.z + vc.w) + (vd.x + vd.y + vd.z + vd.w) +
          (ve.x + ve.y + ve.z + ve.w);
  }
  ax = dppredsum(ax);
  if ((threadIdx.x & 63) == 63)
    sink[blockIdx.x * 4 + (threadIdx.x >> 6)] = ax;
}

// ---- k_rowstats: BYTE-IDENTICAL to R6 (66-70 us reference point) ----
__global__ __launch_bounds__(256) void k_rowstats(
    const float* __restrict__ o1, const float* __restrict__ o2,
    const float* __restrict__ o3, const float* __restrict__ o4,
    const float* __restrict__ os, const int* __restrict__ tg,
    float* __restrict__ ws) {
  const int lane = threadIdx.x & 63;
  const int wv = threadIdx.x >> 6;         // 0..3
  const int row = blockIdx.x;
  const size_t base = (size_t)row * NC;
  const int f = (threadIdx.x < NF4) ? (int)threadIdx.x : 0;  // float4 idx
  const bool act = threadIdx.x < NF4;

  float g1 = 0.f, g2 = 0.f, g3 = 0.f, g4 = 0.f, gs = 0.f;
  if (wv == 0) {
    const int target = tg[row];
    g1 = o1[base + target];
    g2 = o2[base + target];
    g3 = o3[base + target];
    g4 = o4[base + target];
    gs = os[base + target];
  }

  const float4 c1 = ((const float4*)(o1 + base))[f];
  const float4 c2 = ((const float4*)(o2 + base))[f];
  const float4 c3 = ((const float4*)(o3 + base))[f];
  const float4 c4 = ((const float4*)(o4 + base))[f];
  const float4 cs = ((const float4*)(os + base))[f];

  float t1[5], t2[5], Z[5], S1[5];
#pragma unroll
  for (int t = 0; t < 5; ++t) {
    t1[t] = -INFINITY; t2[t] = -INFINITY; Z[t] = 0.f; S1[t] = 0.f;
  }
  float Z1 = 0.f, Z20 = 0.f;
  const float K20 = LOG2E / 20.0f;

  if (act) {
#pragma unroll
    for (int e = 0; e < 4; ++e) {
      float w0 = f4get(c1, e);
      float w1 = f4get(c2, e);
      float w2 = f4get(c3, e);
      float w3 = f4get(c4, e);
      float wsv = f4get(cs, e);
      float wm = ((w0 + w1) + w2 + w3) * 0.25f;  // mimic — keep this op order
      float w[5] = {w0, w1, w2, w3, wm};
#pragma unroll
      for (int t = 0; t < 5; ++t) {
        t2[t] = fmaxf(t2[t], fminf(t1[t], w[t]));
        t1[t] = fmaxf(t1[t], w[t]);
        float et = fexp2(w[t] * K20);
        Z[t] += et;
        S1[t] = fmaf(et, w[t] - wsv, S1[t]);
      }
      Z1 += fexp2(wsv * LOG2E);
      Z20 += fexp2(wsv * K20);
    }
  }

#pragma unroll
  for (int t = 0; t < 5; ++t) dppredtop2(t1[t], t2[t]);
#pragma unroll
  for (int t = 0; t < 5; ++t) { Z[t] = dppredsum(Z[t]); S1[t] = dppredsum(S1[t]); }
  Z1 = dppredsum(Z1);
  Z20 = dppredsum(Z20);

  __shared__ float sred[4][22];
  if (lane == 63) {
#pragma unroll
    for (int t = 0; t < 5; ++t) {
      sred[wv][t] = t1[t];
      sred[wv][5 + t] = t2[t];
      sred[wv][10 + t] = Z[t];
      sred[wv][15 + t] = S1[t];
    }
    sred[wv][20] = Z1;
    sred[wv][21] = Z20;
  }
  __syncthreads();

  if (threadIdx.x == 0) {
    float T1[5], T2[5], ZZ[5], SS[5], z1, z20;
#pragma unroll
    for (int t = 0; t < 5; ++t) {
      T1[t] = sred[0][t]; T2[t] = sred[0][5 + t];
      ZZ[t] = sred[0][10 + t]; SS[t] = sred[0][15 + t];
    }
    z1 = sred[0][20]; z20 = sred[0][21];
#pragma unroll
    for (int w = 1; w < 4; ++w) {
#pragma unroll
      for (int t = 0; t < 5; ++t) {
        float a1 = sred[w][t], a2 = sred[w][5 + t];
        float lo = fminf(T1[t], a1);
        T1[t] = fmaxf(T1[t], a1);
        T2[t] = fmaxf(fmaxf(T2[t], a2), lo);
        ZZ[t] += sred[w][10 + t];
        SS[t] += sred[w][15 + t];
      }
      z1 += sred[w][20];
      z20 += sred[w][21];
    }

    const float gm = ((g1 + g2) + g3 + g4) * 0.25f;  // same op order as wm
    float gg[5] = {g1, g2, g3, g4, gm};

    const float lse_s = flog2(z20) * LN2;      // logsumexp(out_s/20)
    const float CE = flog2(z1) * LN2 - gs;     // -log_softmax(out_s)[target]

#pragma unroll
    for (int t = 0; t < 5; ++t) {
      float lse_t = flog2(ZZ[t]) * LN2;
      float KD = 400.0f * (SS[t] / (20.0f * ZZ[t]) - lse_t + lse_s);
      float margin = (T1[t] == gg[t]) ? (T1[t] - T2[t]) : 0.0f;
      ws[(size_t)t * NB + row] = margin;
      ws[(size_t)(5 + t) * NB + row] = gg[t];
      ws[(size_t)(10 + t) * NB + row] = KD;
    }
    ws[(size_t)15 * NB + row] = CE;
    ws[(size_t)16 * NB + row] = fminf(fminf(g1, g2), fminf(g3, g4));
    ws[(size_t)17 * NB + row] = fmaxf(fmaxf(T1[0], T1[1]), fmaxf(T1[2], T1[3]));
  }
}

// Single block: global min/max over the two 8192-row arrays (64 KB) ->
// shift & maxp; also zeroes out[0] for k_loss's atomics.
__global__ __launch_bounds__(1024) void k_minmax(float* __restrict__ ws,
                                                 float* __restrict__ out) {
  const int tid = threadIdx.x;
  const int lane = tid & 63, wv = tid >> 6;
  __shared__ float sA[16], sB[16];

  float mn = INFINITY, mx = -INFINITY;
  for (int r = tid; r < NB; r += 1024) {
    mn = fminf(mn, ws[(size_t)16 * NB + r]);
    mx = fmaxf(mx, ws[(size_t)17 * NB + r]);
  }
  mn = wredmin(mn);
  mx = wredmax(mx);
  if (lane == 0) { sA[wv] = mn; sB[wv] = mx; }
  __syncthreads();
  if (tid == 0) {
    float a = sA[0], b = sB[0];
    for (int i = 1; i < 16; ++i) { a = fminf(a, sA[i]); b = fmaxf(b, sB[i]); }
    float shift = (a < 0.0f) ? (-a + 1e-5f) : 0.0f;
    ws[(size_t)18 * NB] = shift;
    ws[(size_t)18 * NB + 1] = b + shift;
    out[0] = 0.0f;
  }
}

// Multi-block weighted-loss reduction; one atomicAdd per block.
__global__ __launch_bounds__(256) void k_loss(const float* __restrict__ ws,
                                              float* __restrict__ out) {
  const int tid = threadIdx.x;
  const int lane = tid & 63, wv = tid >> 6;
  const int r = blockIdx.x * 256 + tid;   // 32 blocks x 256 = 8192 rows
  __shared__ float sA[4];

  const float shift = ws[(size_t)18 * NB];
  const float maxp = ws[(size_t)18 * NB + 1];
  const float K6 = LOG2E / 6.0f;

  float m[5], e[5];
#pragma unroll
  for (int t = 0; t < 5; ++t) m[t] = ws[(size_t)t * NB + r];
  float pm = fmaxf(fmaxf(fmaxf(m[0], m[1]), fmaxf(m[2], m[3])), m[4]);
  float Zl = 0.0f;
#pragma unroll
  for (int t = 0; t < 5; ++t) { e[t] = fexp2((m[t] - pm) * K6); Zl += e[t]; }
  float ce = ws[(size_t)15 * NB + r];
  float rl = 0.0f;
#pragma unroll
  for (int t = 0; t < 5; ++t) {
    float g = ws[(size_t)(5 + t) * NB + r];
    float kd = ws[(size_t)(10 + t) * NB + r];
    float w2 = (g + shift) / maxp;
    float loss = (1.0f - w2) * ce + w2 * kd;
    rl += e[t] * loss;
  }
  float acc = rl / Zl;

  acc = wredsum(acc);
  if (lane == 0) sA[wv] = acc;
  __syncthreads();
  if (tid == 0) {
    float tot = (sA[0] + sA[1]) + (sA[2] + sA[3]);
    atomicAdd(out, tot * (1.0f / 8192.0f));
  }
}

extern "C" void kernel_launch(void* const* d_in, const int* in_sizes, int n_in,
                              void* d_out, int out_size, void* d_ws, size_t ws_size,
                              hipStream_t stream) {
  const float* o1 = (const float*)d_in[0];
  const float* o2 = (const float*)d_in[1];
  const float* o3 = (const float*)d_in[2];
  const float* o4 = (const float*)d_in[3];
  const float* os = (const float*)d_in[4];
  const int* tg = (const int*)d_in[5];
  float* ws = (float*)d_ws;
  float* out = (float*)d_out;

  // BW probe of the exact 5-stream read pattern (also L3-warms the inputs
  // for k_rowstats). 1024 blocks = 16 waves/CU, ~8 iterations/thread.
  k_probe<<<1024, 256, 0, stream>>>(
      (const float4*)o1, (const float4*)o2, (const float4*)o3,
      (const float4*)o4, (const float4*)os, ws + (size_t)20 * NB);

  k_rowstats<<<NB, 256, 0, stream>>>(o1, o2, o3, o4, os, tg, ws);
  k_minmax<<<1, 1024, 0, stream>>>(ws, out);
  k_loss<<<NB / 256, 256, 0, stream>>>(ws, out);
}

// Round 10
// 195.400 us; speedup vs baseline: 1.1492x; 1.1492x over previous
//
#include <hip/hip_runtime.h>
#include <math.h>

#define NB 8192      // batch rows
#define NC 1000      // classes
#define NF4 250      // NC / 4 float4s per row

// ws layout (floats, stride NB):
//  [0..4]   margin per branch
//  [5..9]   gathered (raw) per branch
//  [10..14] KD per branch
//  [15]     CE
//  [16]     row min of gathered over 4 real teachers
//  [17]     row max of row-maxes over 4 real teachers
//  [18*NB + 0] shift  (written by k_minmax)
//  [18*NB + 1] maxp   (written by k_minmax)
//  [20*NB ...] touch sink (never read back)

#define LOG2E 1.4426950408889634f
#define LN2   0.6931471805599453f

__device__ __forceinline__ float fexp2(float x) { return __builtin_amdgcn_exp2f(x); }
__device__ __forceinline__ float flog2(float x) { return __builtin_amdgcn_logf(x); }

// ---------------- DPP wave reductions (VALU pipe, not DS) ----------------
template <int CTRL>
__device__ __forceinline__ float dpp_mov(float v, float ident) {
  return __uint_as_float((unsigned)__builtin_amdgcn_update_dpp(
      (int)__float_as_uint(ident), (int)__float_as_uint(v), CTRL, 0xF, 0xF,
      false));
}

__device__ __forceinline__ float dppredsum(float v) {
  v += dpp_mov<0x111>(v, 0.f);
  v += dpp_mov<0x112>(v, 0.f);
  v += dpp_mov<0x114>(v, 0.f);
  v += dpp_mov<0x118>(v, 0.f);
  v += dpp_mov<0x142>(v, 0.f);
  v += dpp_mov<0x143>(v, 0.f);
  return v;  // lane 63 = full sum
}

__device__ __forceinline__ void dppredtop2(float& t1, float& t2) {
  const float NI = -INFINITY;
#define T2STEP(C)                                   \
  {                                                 \
    float i1 = dpp_mov<C>(t1, NI);                  \
    float i2 = dpp_mov<C>(t2, NI);                  \
    t2 = fmaxf(fmaxf(t2, i2), fminf(t1, i1));       \
    t1 = fmaxf(t1, i1);                             \
  }
  T2STEP(0x111) T2STEP(0x112) T2STEP(0x114) T2STEP(0x118)
  T2STEP(0x142) T2STEP(0x143)
#undef T2STEP
}

// shfl-based helpers (only used in the tiny finalize kernels)
__device__ __forceinline__ float wredsum(float v) {
#pragma unroll
  for (int m = 32; m >= 1; m >>= 1) v += __shfl_xor(v, m, 64);
  return v;
}
__device__ __forceinline__ float wredmax(float v) {
#pragma unroll
  for (int m = 32; m >= 1; m >>= 1) v = fmaxf(v, __shfl_xor(v, m, 64));
  return v;
}
__device__ __forceinline__ float wredmin(float v) {
#pragma unroll
  for (int m = 32; m >= 1; m >>= 1) v = fminf(v, __shfl_xor(v, m, 64));
  return v;
}
__device__ __forceinline__ float f4get(const float4& v, int e) {
  return e == 0 ? v.x : e == 1 ? v.y : e == 2 ? v.z : v.w;
}

// ---------------- PAGE-TOUCH MINI-PROBE ----------------
// R9 finding: after a full-sweep read of the inputs, the identical
// k_rowstats ran 68 -> 50 us (FETCH unchanged). Hypothesized mechanism:
// address-translation warming (per-XCD UTCL2). This kernel touches one
// float per 64 KB of every input tensor (500 slots x 5 tensors). 64 blocks
// so every XCD (blocks round-robin XCDs) walks ALL pages redundantly.
// Cost ~3-5 us vs the full probe's 54 us.
__global__ __launch_bounds__(256) void k_touch(
    const float* __restrict__ a, const float* __restrict__ b,
    const float* __restrict__ c, const float* __restrict__ d,
    const float* __restrict__ e, float* __restrict__ sink) {
  float ax = 0.f;
#pragma unroll
  for (int k = 0; k < 2; ++k) {
    const int slot = threadIdx.x + k * 256;   // 0..511; 500 valid
    if (slot < 500) {
      const size_t off = (size_t)slot * 16384;  // 64 KB stride in floats
      ax += a[off] + b[off] + c[off] + d[off] + e[off];
    }
  }
  ax = dppredsum(ax);
  if ((threadIdx.x & 63) == 63)
    sink[blockIdx.x * 4 + (threadIdx.x >> 6)] = ax;
}

// ---- k_rowstats: BYTE-IDENTICAL to R6 (66-70 us cold reference) ----
__global__ __launch_bounds__(256) void k_rowstats(
    const float* __restrict__ o1, const float* __restrict__ o2,
    const float* __restrict__ o3, const float* __restrict__ o4,
    const float* __restrict__ os, const int* __restrict__ tg,
    float* __restrict__ ws) {
  const int lane = threadIdx.x & 63;
  const int wv = threadIdx.x >> 6;         // 0..3
  const int row = blockIdx.x;
  const size_t base = (size_t)row * NC;
  const int f = (threadIdx.x < NF4) ? (int)threadIdx.x : 0;  // float4 idx
  const bool act = threadIdx.x < NF4;

  float g1 = 0.f, g2 = 0.f, g3 = 0.f, g4 = 0.f, gs = 0.f;
  if (wv == 0) {
    const int target = tg[row];
    g1 = o1[base + target];
    g2 = o2[base + target];
    g3 = o3[base + target];
    g4 = o4[base + target];
    gs = os[base + target];
  }

  const float4 c1 = ((const float4*)(o1 + base))[f];
  const float4 c2 = ((const float4*)(o2 + base))[f];
  const float4 c3 = ((const float4*)(o3 + base))[f];
  const float4 c4 = ((const float4*)(o4 + base))[f];
  const float4 cs = ((const float4*)(os + base))[f];

  float t1[5], t2[5], Z[5], S1[5];
#pragma unroll
  for (int t = 0; t < 5; ++t) {
    t1[t] = -INFINITY; t2[t] = -INFINITY; Z[t] = 0.f; S1[t] = 0.f;
  }
  float Z1 = 0.f, Z20 = 0.f;
  const float K20 = LOG2E / 20.0f;

  if (act) {
#pragma unroll
    for (int e = 0; e < 4; ++e) {
      float w0 = f4get(c1, e);
      float w1 = f4get(c2, e);
      float w2 = f4get(c3, e);
      float w3 = f4get(c4, e);
      float wsv = f4get(cs, e);
      float wm = ((w0 + w1) + w2 + w3) * 0.25f;  // mimic — keep this op order
      float w[5] = {w0, w1, w2, w3, wm};
#pragma unroll
      for (int t = 0; t < 5; ++t) {
        t2[t] = fmaxf(t2[t], fminf(t1[t], w[t]));
        t1[t] = fmaxf(t1[t], w[t]);
        float et = fexp2(w[t] * K20);
        Z[t] += et;
        S1[t] = fmaf(et, w[t] - wsv, S1[t]);
      }
      Z1 += fexp2(wsv * LOG2E);
      Z20 += fexp2(wsv * K20);
    }
  }

#pragma unroll
  for (int t = 0; t < 5; ++t) dppredtop2(t1[t], t2[t]);
#pragma unroll
  for (int t = 0; t < 5; ++t) { Z[t] = dppredsum(Z[t]); S1[t] = dppredsum(S1[t]); }
  Z1 = dppredsum(Z1);
  Z20 = dppredsum(Z20);

  __shared__ float sred[4][22];
  if (lane == 63) {
#pragma unroll
    for (int t = 0; t < 5; ++t) {
      sred[wv][t] = t1[t];
      sred[wv][5 + t] = t2[t];
      sred[wv][10 + t] = Z[t];
      sred[wv][15 + t] = S1[t];
    }
    sred[wv][20] = Z1;
    sred[wv][21] = Z20;
  }
  __syncthreads();

  if (threadIdx.x == 0) {
    float T1[5], T2[5], ZZ[5], SS[5], z1, z20;
#pragma unroll
    for (int t = 0; t < 5; ++t) {
      T1[t] = sred[0][t]; T2[t] = sred[0][5 + t];
      ZZ[t] = sred[0][10 + t]; SS[t] = sred[0][15 + t];
    }
    z1 = sred[0][20]; z20 = sred[0][21];
#pragma unroll
    for (int w = 1; w < 4; ++w) {
#pragma unroll
      for (int t = 0; t < 5; ++t) {
        float a1 = sred[w][t], a2 = sred[w][5 + t];
        float lo = fminf(T1[t], a1);
        T1[t] = fmaxf(T1[t], a1);
        T2[t] = fmaxf(fmaxf(T2[t], a2), lo);
        ZZ[t] += sred[w][10 + t];
        SS[t] += sred[w][15 + t];
      }
      z1 += sred[w][20];
      z20 += sred[w][21];
    }

    const float gm = ((g1 + g2) + g3 + g4) * 0.25f;  // same op order as wm
    float gg[5] = {g1, g2, g3, g4, gm};

    const float lse_s = flog2(z20) * LN2;      // logsumexp(out_s/20)
    const float CE = flog2(z1) * LN2 - gs;     // -log_softmax(out_s)[target]

#pragma unroll
    for (int t = 0; t < 5; ++t) {
      float lse_t = flog2(ZZ[t]) * LN2;
      float KD = 400.0f * (SS[t] / (20.0f * ZZ[t]) - lse_t + lse_s);
      float margin = (T1[t] == gg[t]) ? (T1[t] - T2[t]) : 0.0f;
      ws[(size_t)t * NB + row] = margin;
      ws[(size_t)(5 + t) * NB + row] = gg[t];
      ws[(size_t)(10 + t) * NB + row] = KD;
    }
    ws[(size_t)15 * NB + row] = CE;
    ws[(size_t)16 * NB + row] = fminf(fminf(g1, g2), fminf(g3, g4));
    ws[(size_t)17 * NB + row] = fmaxf(fmaxf(T1[0], T1[1]), fmaxf(T1[2], T1[3]));
  }
}

// Single block: global min/max over the two 8192-row arrays (64 KB) ->
// shift & maxp; also zeroes out[0] for k_loss's atomics.
__global__ __launch_bounds__(1024) void k_minmax(float* __restrict__ ws,
                                                 float* __restrict__ out) {
  const int tid = threadIdx.x;
  const int lane = tid & 63, wv = tid >> 6;
  __shared__ float sA[16], sB[16];

  float mn = INFINITY, mx = -INFINITY;
  for (int r = tid; r < NB; r += 1024) {
    mn = fminf(mn, ws[(size_t)16 * NB + r]);
    mx = fmaxf(mx, ws[(size_t)17 * NB + r]);
  }
  mn = wredmin(mn);
  mx = wredmax(mx);
  if (lane == 0) { sA[wv] = mn; sB[wv] = mx; }
  __syncthreads();
  if (tid == 0) {
    float a = sA[0], b = sB[0];
    for (int i = 1; i < 16; ++i) { a = fminf(a, sA[i]); b = fmaxf(b, sB[i]); }
    float shift = (a < 0.0f) ? (-a + 1e-5f) : 0.0f;
    ws[(size_t)18 * NB] = shift;
    ws[(size_t)18 * NB + 1] = b + shift;
    out[0] = 0.0f;
  }
}

// Multi-block weighted-loss reduction; one atomicAdd per block.
__global__ __launch_bounds__(256) void k_loss(const float* __restrict__ ws,
                                              float* __restrict__ out) {
  const int tid = threadIdx.x;
  const int lane = tid & 63, wv = tid >> 6;
  const int r = blockIdx.x * 256 + tid;   // 32 blocks x 256 = 8192 rows
  __shared__ float sA[4];

  const float shift = ws[(size_t)18 * NB];
  const float maxp = ws[(size_t)18 * NB + 1];
  const float K6 = LOG2E / 6.0f;

  float m[5], e[5];
#pragma unroll
  for (int t = 0; t < 5; ++t) m[t] = ws[(size_t)t * NB + r];
  float pm = fmaxf(fmaxf(fmaxf(m[0], m[1]), fmaxf(m[2], m[3])), m[4]);
  float Zl = 0.0f;
#pragma unroll
  for (int t = 0; t < 5; ++t) { e[t] = fexp2((m[t] - pm) * K6); Zl += e[t]; }
  float ce = ws[(size_t)15 * NB + r];
  float rl = 0.0f;
#pragma unroll
  for (int t = 0; t < 5; ++t) {
    float g = ws[(size_t)(5 + t) * NB + r];
    float kd = ws[(size_t)(10 + t) * NB + r];
    float w2 = (g + shift) / maxp;
    float loss = (1.0f - w2) * ce + w2 * kd;
    rl += e[t] * loss;
  }
  float acc = rl / Zl;

  acc = wredsum(acc);
  if (lane == 0) sA[wv] = acc;
  __syncthreads();
  if (tid == 0) {
    float tot = (sA[0] + sA[1]) + (sA[2] + sA[3]);
    atomicAdd(out, tot * (1.0f / 8192.0f));
  }
}

extern "C" void kernel_launch(void* const* d_in, const int* in_sizes, int n_in,
                              void* d_out, int out_size, void* d_ws, size_t ws_size,
                              hipStream_t stream) {
  const float* o1 = (const float*)d_in[0];
  const float* o2 = (const float*)d_in[1];
  const float* o3 = (const float*)d_in[2];
  const float* o4 = (const float*)d_in[3];
  const float* os = (const float*)d_in[4];
  const int* tg = (const int*)d_in[5];
  float* ws = (float*)d_ws;
  float* out = (float*)d_out;

  // page-touch warming pass (~3-5 us); see k_touch comment
  k_touch<<<64, 256, 0, stream>>>(o1, o2, o3, o4, os, ws + (size_t)20 * NB);

  k_rowstats<<<NB, 256, 0, stream>>>(o1, o2, o3, o4, os, tg, ws);
  k_minmax<<<1, 1024, 0, stream>>>(ws, out);
  k_loss<<<NB / 256, 256, 0, stream>>>(ws, out);
}

// Round 11
// 191.185 us; speedup vs baseline: 1.1746x; 1.0220x over previous
//
#include <hip/hip_runtime.h>
#include <math.h>

#define NB 8192      // batch rows
#define NC 1000      // classes
#define NF4 250      // NC / 4 float4s per row

// ws layout (floats, stride NB):
//  [0..4]   margin per branch
//  [5..9]   gathered (raw) per branch
//  [10..14] KD per branch
//  [15]     CE
//  [16]     row min of gathered over 4 real teachers
//  [17]     row max of row-maxes over 4 real teachers
//  [18*NB + 0] shift  (written by k_minmax)
//  [18*NB + 1] maxp   (written by k_minmax)

#define LOG2E 1.4426950408889634f
#define LN2   0.6931471805599453f

__device__ __forceinline__ float fexp2(float x) { return __builtin_amdgcn_exp2f(x); }
__device__ __forceinline__ float flog2(float x) { return __builtin_amdgcn_logf(x); }

// ---------------- DPP wave reductions (VALU pipe, not DS) ----------------
template <int CTRL>
__device__ __forceinline__ float dpp_mov(float v, float ident) {
  return __uint_as_float((unsigned)__builtin_amdgcn_update_dpp(
      (int)__float_as_uint(ident), (int)__float_as_uint(v), CTRL, 0xF, 0xF,
      false));
}

__device__ __forceinline__ float dppredsum(float v) {
  v += dpp_mov<0x111>(v, 0.f);
  v += dpp_mov<0x112>(v, 0.f);
  v += dpp_mov<0x114>(v, 0.f);
  v += dpp_mov<0x118>(v, 0.f);
  v += dpp_mov<0x142>(v, 0.f);
  v += dpp_mov<0x143>(v, 0.f);
  return v;  // lane 63 = full sum
}

__device__ __forceinline__ void dppredtop2(float& t1, float& t2) {
  const float NI = -INFINITY;
#define T2STEP(C)                                   \
  {                                                 \
    float i1 = dpp_mov<C>(t1, NI);                  \
    float i2 = dpp_mov<C>(t2, NI);                  \
    t2 = fmaxf(fmaxf(t2, i2), fminf(t1, i1));       \
    t1 = fmaxf(t1, i1);                             \
  }
  T2STEP(0x111) T2STEP(0x112) T2STEP(0x114) T2STEP(0x118)
  T2STEP(0x142) T2STEP(0x143)
#undef T2STEP
}

// shfl-based helpers (only used in the tiny finalize kernels)
__device__ __forceinline__ float wredsum(float v) {
#pragma unroll
  for (int m = 32; m >= 1; m >>= 1) v += __shfl_xor(v, m, 64);
  return v;
}
__device__ __forceinline__ float wredmax(float v) {
#pragma unroll
  for (int m = 32; m >= 1; m >>= 1) v = fmaxf(v, __shfl_xor(v, m, 64));
  return v;
}
__device__ __forceinline__ float wredmin(float v) {
#pragma unroll
  for (int m = 32; m >= 1; m >>= 1) v = fminf(v, __shfl_xor(v, m, 64));
  return v;
}
__device__ __forceinline__ float f4get(const float4& v, int e) {
  return e == 0 ? v.x : e == 1 ? v.y : e == 2 ? v.z : v.w;
}

// One 128-thread block (2 waves) per row; each lane holds 2 float4s per
// tensor -> 10 loads in flight per thread (probe-parity MLP) while keeping
// R6's winning block-per-row dispatch pattern. Wave 0 covers float4s
// 0..124, wave 1 covers 125..249 (second load masked for lane>=61).
__global__ __launch_bounds__(128) void k_rowstats(
    const float* __restrict__ o1, const float* __restrict__ o2,
    const float* __restrict__ o3, const float* __restrict__ o4,
    const float* __restrict__ os, const int* __restrict__ tg,
    float* __restrict__ ws) {
  const int lane = threadIdx.x & 63;
  const int wv = threadIdx.x >> 6;         // 0..1
  const int row = blockIdx.x;
  const size_t base = (size_t)row * NC;
  const int f0 = wv * 125 + lane;          // always valid (<250)
  const bool act1 = lane < 61;             // f0+64 < wave's 125-slot window
  const int f1 = act1 ? f0 + 64 : 0;

  // target gathers: wave 0 only — issue first, overlap bulk loads
  float g1 = 0.f, g2 = 0.f, g3 = 0.f, g4 = 0.f, gs = 0.f;
  if (wv == 0) {
    const int target = tg[row];
    g1 = o1[base + target];
    g2 = o2[base + target];
    g3 = o3[base + target];
    g4 = o4[base + target];
    gs = os[base + target];
  }

  const float4* p1 = (const float4*)(o1 + base);
  const float4* p2 = (const float4*)(o2 + base);
  const float4* p3 = (const float4*)(o3 + base);
  const float4* p4 = (const float4*)(o4 + base);
  const float4* p5 = (const float4*)(os + base);

  // 10 bulk loads, all in flight at once
  const float4 a1 = p1[f0], b1 = p1[f1];
  const float4 a2 = p2[f0], b2 = p2[f1];
  const float4 a3 = p3[f0], b3 = p3[f1];
  const float4 a4 = p4[f0], b4 = p4[f1];
  const float4 a5 = p5[f0], b5 = p5[f1];

  float t1[5], t2[5], Z[5], S1[5];
#pragma unroll
  for (int t = 0; t < 5; ++t) {
    t1[t] = -INFINITY; t2[t] = -INFINITY; Z[t] = 0.f; S1[t] = 0.f;
  }
  float Z1 = 0.f, Z20 = 0.f;
  const float K20 = LOG2E / 20.0f;

#pragma unroll
  for (int half = 0; half < 2; ++half) {
    if (half == 1 && !act1) break;
#pragma unroll
    for (int e = 0; e < 4; ++e) {
      float w0 = f4get(half ? b1 : a1, e);
      float w1 = f4get(half ? b2 : a2, e);
      float w2 = f4get(half ? b3 : a3, e);
      float w3 = f4get(half ? b4 : a4, e);
      float wsv = f4get(half ? b5 : a5, e);
      float wm = ((w0 + w1) + w2 + w3) * 0.25f;  // mimic — keep this op order
      float w[5] = {w0, w1, w2, w3, wm};
#pragma unroll
      for (int t = 0; t < 5; ++t) {
        t2[t] = fmaxf(t2[t], fminf(t1[t], w[t]));
        t1[t] = fmaxf(t1[t], w[t]);
        float et = fexp2(w[t] * K20);
        Z[t] += et;
        S1[t] = fmaf(et, w[t] - wsv, S1[t]);
      }
      Z1 += fexp2(wsv * LOG2E);
      Z20 += fexp2(wsv * K20);
    }
  }

  // wave-level reductions on the VALU pipe (result in lane 63)
#pragma unroll
  for (int t = 0; t < 5; ++t) dppredtop2(t1[t], t2[t]);
#pragma unroll
  for (int t = 0; t < 5; ++t) { Z[t] = dppredsum(Z[t]); S1[t] = dppredsum(S1[t]); }
  Z1 = dppredsum(Z1);
  Z20 = dppredsum(Z20);

  // cross-wave combine via LDS: 22 partials per wave
  __shared__ float sred[2][22];
  if (lane == 63) {
#pragma unroll
    for (int t = 0; t < 5; ++t) {
      sred[wv][t] = t1[t];
      sred[wv][5 + t] = t2[t];
      sred[wv][10 + t] = Z[t];
      sred[wv][15 + t] = S1[t];
    }
    sred[wv][20] = Z1;
    sred[wv][21] = Z20;
  }
  __syncthreads();

  if (threadIdx.x == 0) {
    float T1[5], T2[5], ZZ[5], SS[5], z1, z20;
#pragma unroll
    for (int t = 0; t < 5; ++t) {
      T1[t] = sred[0][t]; T2[t] = sred[0][5 + t];
      ZZ[t] = sred[0][10 + t]; SS[t] = sred[0][15 + t];
    }
    z1 = sred[0][20]; z20 = sred[0][21];
#pragma unroll
    for (int t = 0; t < 5; ++t) {
      float a1v = sred[1][t], a2v = sred[1][5 + t];
      float lo = fminf(T1[t], a1v);
      T1[t] = fmaxf(T1[t], a1v);
      T2[t] = fmaxf(fmaxf(T2[t], a2v), lo);
      ZZ[t] += sred[1][10 + t];
      SS[t] += sred[1][15 + t];
    }
    z1 += sred[1][20];
    z20 += sred[1][21];

    const float gm = ((g1 + g2) + g3 + g4) * 0.25f;  // same op order as wm
    float gg[5] = {g1, g2, g3, g4, gm};

    const float lse_s = flog2(z20) * LN2;      // logsumexp(out_s/20)
    const float CE = flog2(z1) * LN2 - gs;     // -log_softmax(out_s)[target]

#pragma unroll
    for (int t = 0; t < 5; ++t) {
      float lse_t = flog2(ZZ[t]) * LN2;
      float KD = 400.0f * (SS[t] / (20.0f * ZZ[t]) - lse_t + lse_s);
      float margin = (T1[t] == gg[t]) ? (T1[t] - T2[t]) : 0.0f;
      ws[(size_t)t * NB + row] = margin;
      ws[(size_t)(5 + t) * NB + row] = gg[t];
      ws[(size_t)(10 + t) * NB + row] = KD;
    }
    ws[(size_t)15 * NB + row] = CE;
    ws[(size_t)16 * NB + row] = fminf(fminf(g1, g2), fminf(g3, g4));
    ws[(size_t)17 * NB + row] = fmaxf(fmaxf(T1[0], T1[1]), fmaxf(T1[2], T1[3]));
  }
}

// Single block: global min/max over the two 8192-row arrays (64 KB) ->
// shift & maxp; also zeroes out[0] for k_loss's atomics.
__global__ __launch_bounds__(1024) void k_minmax(float* __restrict__ ws,
                                                 float* __restrict__ out) {
  const int tid = threadIdx.x;
  const int lane = tid & 63, wv = tid >> 6;
  __shared__ float sA[16], sB[16];

  float mn = INFINITY, mx = -INFINITY;
  for (int r = tid; r < NB; r += 1024) {
    mn = fminf(mn, ws[(size_t)16 * NB + r]);
    mx = fmaxf(mx, ws[(size_t)17 * NB + r]);
  }
  mn = wredmin(mn);
  mx = wredmax(mx);
  if (lane == 0) { sA[wv] = mn; sB[wv] = mx; }
  __syncthreads();
  if (tid == 0) {
    float a = sA[0], b = sB[0];
    for (int i = 1; i < 16; ++i) { a = fminf(a, sA[i]); b = fmaxf(b, sB[i]); }
    float shift = (a < 0.0f) ? (-a + 1e-5f) : 0.0f;
    ws[(size_t)18 * NB] = shift;
    ws[(size_t)18 * NB + 1] = b + shift;
    out[0] = 0.0f;
  }
}

// Multi-block weighted-loss reduction; one atomicAdd per block.
__global__ __launch_bounds__(256) void k_loss(const float* __restrict__ ws,
                                              float* __restrict__ out) {
  const int tid = threadIdx.x;
  const int lane = tid & 63, wv = tid >> 6;
  const int r = blockIdx.x * 256 + tid;   // 32 blocks x 256 = 8192 rows
  __shared__ float sA[4];

  const float shift = ws[(size_t)18 * NB];
  const float maxp = ws[(size_t)18 * NB + 1];
  const float K6 = LOG2E / 6.0f;

  float m[5], e[5];
#pragma unroll
  for (int t = 0; t < 5; ++t) m[t] = ws[(size_t)t * NB + r];
  float pm = fmaxf(fmaxf(fmaxf(m[0], m[1]), fmaxf(m[2], m[3])), m[4]);
  float Zl = 0.0f;
#pragma unroll
  for (int t = 0; t < 5; ++t) { e[t] = fexp2((m[t] - pm) * K6); Zl += e[t]; }
  float ce = ws[(size_t)15 * NB + r];
  float rl = 0.0f;
#pragma unroll
  for (int t = 0; t < 5; ++t) {
    float g = ws[(size_t)(5 + t) * NB + r];
    float kd = ws[(size_t)(10 + t) * NB + r];
    float w2 = (g + shift) / maxp;
    float loss = (1.0f - w2) * ce + w2 * kd;
    rl += e[t] * loss;
  }
  float acc = rl / Zl;

  acc = wredsum(acc);
  if (lane == 0) sA[wv] = acc;
  __syncthreads();
  if (tid == 0) {
    float tot = (sA[0] + sA[1]) + (sA[2] + sA[3]);
    atomicAdd(out, tot * (1.0f / 8192.0f));
  }
}

extern "C" void kernel_launch(void* const* d_in, const int* in_sizes, int n_in,
                              void* d_out, int out_size, void* d_ws, size_t ws_size,
                              hipStream_t stream) {
  const float* o1 = (const float*)d_in[0];
  const float* o2 = (const float*)d_in[1];
  const float* o3 = (const float*)d_in[2];
  const float* o4 = (const float*)d_in[3];
  const float* os = (const float*)d_in[4];
  const int* tg = (const int*)d_in[5];
  float* ws = (float*)d_ws;
  float* out = (float*)d_out;

  k_rowstats<<<NB, 128, 0, stream>>>(o1, o2, o3, o4, os, tg, ws);
  k_minmax<<<1, 1024, 0, stream>>>(ws, out);
  k_loss<<<NB / 256, 256, 0, stream>>>(ws, out);
}